// Round 1
// baseline (674.124 us; speedup 1.0000x reference)
//
#include <hip/hip_runtime.h>

#define PH_ 7
#define PW_ 7
#define C_ 256
#define H_ 200
#define W_ 272
#define HW_ (H_*W_)
#define CB 8                 // channels per work item
#define NCG (C_/CB)          // 32 channel groups
#define NBIN (PH_*PW_)       // 49
#define NITEM (NCG*NBIN)     // 1568

__global__ __launch_bounds__(256, 4)
void roialign_kernel(const float* __restrict__ feat,
                     const float* __restrict__ rois,
                     float* __restrict__ out) {
  // per-(ph,iy): {int y0*W, hy*vy, ly*vy, int y1i*W}
  // per-(pw,ix): {int x0,   hx*vx*0.25, lx*vx*0.25, int x1i}
  __shared__ float4 yp[PH_*2];
  __shared__ float4 xp[PW_*2];
  __shared__ int sbase;

  const int n = blockIdx.x;
  const int tid = threadIdx.x;
  const float* roi = rois + (size_t)n * 5;

  if (tid < 28) {
    float x1 = roi[1] * 0.0625f, y1 = roi[2] * 0.0625f;
    float x2 = roi[3] * 0.0625f, y2 = roi[4] * 0.0625f;
    float roi_w = fmaxf(x2 - x1, 1.0f);
    float roi_h = fmaxf(y2 - y1, 1.0f);
    float bin_w = roi_w * (1.0f / 7.0f);
    float bin_h = roi_h * (1.0f / 7.0f);
    if (tid == 0) {
      int b = (int)roi[0];
      sbase = b * C_ * HW_;
    }
    if (tid < 14) {
      int ph = tid >> 1, iy = tid & 1;
      float y = y1 + (float)ph * bin_h + ((float)iy + 0.5f) * bin_h * 0.5f;
      float v = (y >= -1.0f && y <= (float)H_) ? 1.0f : 0.0f;
      float yc = fminf(fmaxf(y, 0.0f), (float)(H_ - 1));
      int y0 = (int)floorf(yc);
      if (y0 > H_ - 1) y0 = H_ - 1;
      int y1i = min(y0 + 1, H_ - 1);
      float ly = yc - (float)y0;
      float hy = 1.0f - ly;
      yp[tid] = make_float4(__int_as_float(y0 * W_), hy * v, ly * v,
                            __int_as_float(y1i * W_));
    } else {
      int t = tid - 14;
      int pw = t >> 1, ix = t & 1;
      float x = x1 + (float)pw * bin_w + ((float)ix + 0.5f) * bin_w * 0.5f;
      float v = (x >= -1.0f && x <= (float)W_) ? 0.25f : 0.0f;
      float xc = fminf(fmaxf(x, 0.0f), (float)(W_ - 1));
      int x0 = (int)floorf(xc);
      if (x0 > W_ - 1) x0 = W_ - 1;
      int x1i = min(x0 + 1, W_ - 1);
      float lx = xc - (float)x0;
      float hx = 1.0f - lx;
      xp[t] = make_float4(__int_as_float(x0), hx * v, lx * v,
                          __int_as_float(x1i));
    }
  }
  __syncthreads();

  const int base = sbase;
  float* outn = out + (size_t)n * (C_ * NBIN);

  for (int e = tid; e < NITEM; e += 256) {
    int cg = e / NBIN;
    int bin = e - cg * NBIN;
    int ph = (bin * 37) >> 8;        // bin / 7 for bin in [0,49)
    int pw = bin - ph * 7;

    float4 ya = yp[ph * 2 + 0];
    float4 yb = yp[ph * 2 + 1];
    float4 xa = xp[pw * 2 + 0];
    float4 xb = xp[pw * 2 + 1];

    int r00 = __float_as_int(ya.x), r01 = __float_as_int(ya.w);
    int r10 = __float_as_int(yb.x), r11 = __float_as_int(yb.w);
    int c00 = __float_as_int(xa.x), c01 = __float_as_int(xa.w);
    int c10 = __float_as_int(xb.x), c11 = __float_as_int(xb.w);

    int o[16];
    float w[16];
    // sample (iy=0, ix=0)
    o[0] = r00 + c00; o[1] = r00 + c01; o[2] = r01 + c00; o[3] = r01 + c01;
    w[0] = ya.y * xa.y; w[1] = ya.y * xa.z; w[2] = ya.z * xa.y; w[3] = ya.z * xa.z;
    // sample (iy=0, ix=1)
    o[4] = r00 + c10; o[5] = r00 + c11; o[6] = r01 + c10; o[7] = r01 + c11;
    w[4] = ya.y * xb.y; w[5] = ya.y * xb.z; w[6] = ya.z * xb.y; w[7] = ya.z * xb.z;
    // sample (iy=1, ix=0)
    o[8] = r10 + c00; o[9] = r10 + c01; o[10] = r11 + c00; o[11] = r11 + c01;
    w[8] = yb.y * xa.y; w[9] = yb.y * xa.z; w[10] = yb.z * xa.y; w[11] = yb.z * xa.z;
    // sample (iy=1, ix=1)
    o[12] = r10 + c10; o[13] = r10 + c11; o[14] = r11 + c10; o[15] = r11 + c11;
    w[12] = yb.y * xb.y; w[13] = yb.y * xb.z; w[14] = yb.z * xb.y; w[15] = yb.z * xb.z;

    const float* p = feat + (size_t)base + (size_t)(cg * CB) * HW_;
    int obase = cg * CB * NBIN + bin;
#pragma unroll
    for (int k = 0; k < CB; ++k) {
      const float* pk = p + (size_t)k * HW_;
      float acc = 0.0f;
#pragma unroll
      for (int q = 0; q < 16; ++q) acc = fmaf(w[q], pk[o[q]], acc);
      outn[obase + k * NBIN] = acc;
    }
  }
}

extern "C" void kernel_launch(void* const* d_in, const int* in_sizes, int n_in,
                              void* d_out, int out_size, void* d_ws, size_t ws_size,
                              hipStream_t stream) {
  const float* feat = (const float*)d_in[0];
  const float* rois = (const float*)d_in[1];
  float* out = (float*)d_out;
  int N = in_sizes[1] / 5;  // rois is (N,5)
  roialign_kernel<<<dim3(N), dim3(256), 0, stream>>>(feat, rois, out);
}

// Round 2
// 343.972 us; speedup vs baseline: 1.9598x; 1.9598x over previous
//
#include <hip/hip_runtime.h>

#define PH_ 7
#define PW_ 7
#define C_ 256
#define H_ 200
#define W_ 272
#define HW_ (H_*W_)
#define CB 8                 // channels per work item
#define NCG (C_/CB)          // 32 channel groups
#define NBIN (PH_*PW_)       // 49
#define NITEM (NCG*NBIN)     // 1568

// 8-byte vector with only 4-byte alignment guarantee (x0 can be odd).
// gfx9+ HSA has unaligned-access-mode on; this still emits global_load_dwordx2.
typedef float f2_t __attribute__((ext_vector_type(2), aligned(4)));

__global__ __launch_bounds__(256, 8)
void roialign_kernel(const float* __restrict__ feat,
                     const float* __restrict__ rois,
                     float* __restrict__ out) {
  // per-(ph,iy): {int y0*W, hy*vy, ly*vy, int y1i*W}
  // per-(pw,ix): {int col,  w_left, w_right, unused}  (weights fold vx*0.25)
  __shared__ float4 yp[PH_*2];
  __shared__ float4 xp[PW_*2];
  __shared__ int sbase;

  const int n = blockIdx.x;
  const int tid = threadIdx.x;
  const float* roi = rois + (size_t)n * 5;

  if (tid < 28) {
    float x1 = roi[1] * 0.0625f, y1 = roi[2] * 0.0625f;
    float x2 = roi[3] * 0.0625f, y2 = roi[4] * 0.0625f;
    float roi_w = fmaxf(x2 - x1, 1.0f);
    float roi_h = fmaxf(y2 - y1, 1.0f);
    float bin_w = roi_w * (1.0f / 7.0f);
    float bin_h = roi_h * (1.0f / 7.0f);
    if (tid == 0) {
      int b = (int)roi[0];
      sbase = b * C_ * HW_;
    }
    if (tid < 14) {
      int ph = tid >> 1, iy = tid & 1;
      float y = y1 + (float)ph * bin_h + ((float)iy + 0.5f) * bin_h * 0.5f;
      float v = (y >= -1.0f && y <= (float)H_) ? 1.0f : 0.0f;
      float yc = fminf(fmaxf(y, 0.0f), (float)(H_ - 1));
      int y0 = (int)floorf(yc);
      if (y0 > H_ - 1) y0 = H_ - 1;
      int y1i = min(y0 + 1, H_ - 1);
      float ly = yc - (float)y0;
      float hy = 1.0f - ly;
      yp[tid] = make_float4(__int_as_float(y0 * W_), hy * v, ly * v,
                            __int_as_float(y1i * W_));
    } else {
      int t = tid - 14;
      int pw = t >> 1, ix = t & 1;
      float x = x1 + (float)pw * bin_w + ((float)ix + 0.5f) * bin_w * 0.5f;
      float v = (x >= -1.0f && x <= (float)W_) ? 0.25f : 0.0f;
      float xc = fminf(fmaxf(x, 0.0f), (float)(W_ - 1));
      int x0 = (int)floorf(xc);
      float lx = xc - (float)x0;
      float hx = 1.0f - lx;
      int c;
      float wl, wr;
      if (x0 >= W_ - 1) {        // clamped: x1i==x0==W-1, lx==0
        c = W_ - 2;
        wl = 0.0f;
        wr = hx * v;             // hx == 1 here
      } else {
        c = x0;
        wl = hx * v;
        wr = lx * v;
      }
      xp[t] = make_float4(__int_as_float(c), wl, wr, 0.0f);
    }
  }
  __syncthreads();

  const int base = sbase;
  float* outn = out + (size_t)n * (C_ * NBIN);

  for (int e = tid; e < NITEM; e += 256) {
    int cg = e / NBIN;
    int bin = e - cg * NBIN;
    int ph = (bin * 37) >> 8;        // bin / 7 for bin in [0,49)
    int pw = bin - ph * 7;

    float4 ya = yp[ph * 2 + 0];
    float4 yb = yp[ph * 2 + 1];
    float4 xa = xp[pw * 2 + 0];
    float4 xb = xp[pw * 2 + 1];

    int r00 = __float_as_int(ya.x), r01 = __float_as_int(ya.w);
    int r10 = __float_as_int(yb.x), r11 = __float_as_int(yb.w);
    int c0  = __float_as_int(xa.x), c1  = __float_as_int(xb.x);

    int o[8];
    float wa[8], wb[8];
    // sample (iy=0, ix=0): rows r00/r01, col c0
    o[0] = r00 + c0; wa[0] = ya.y * xa.y; wb[0] = ya.y * xa.z;
    o[1] = r01 + c0; wa[1] = ya.z * xa.y; wb[1] = ya.z * xa.z;
    // sample (iy=0, ix=1): rows r00/r01, col c1
    o[2] = r00 + c1; wa[2] = ya.y * xb.y; wb[2] = ya.y * xb.z;
    o[3] = r01 + c1; wa[3] = ya.z * xb.y; wb[3] = ya.z * xb.z;
    // sample (iy=1, ix=0)
    o[4] = r10 + c0; wa[4] = yb.y * xa.y; wb[4] = yb.y * xa.z;
    o[5] = r11 + c0; wa[5] = yb.z * xa.y; wb[5] = yb.z * xa.z;
    // sample (iy=1, ix=1)
    o[6] = r10 + c1; wa[6] = yb.y * xb.y; wb[6] = yb.y * xb.z;
    o[7] = r11 + c1; wa[7] = yb.z * xb.y; wb[7] = yb.z * xb.z;

    const float* p = feat + (size_t)base + (size_t)(cg * CB) * HW_;
    int obase = cg * CB * NBIN + bin;
#pragma unroll
    for (int k = 0; k < CB; ++k) {
      const float* pk = p + (size_t)k * HW_;
      float acc = 0.0f;
#pragma unroll
      for (int q = 0; q < 8; ++q) {
        f2_t v = *(const f2_t*)(pk + o[q]);
        acc = fmaf(wa[q], v.x, acc);
        acc = fmaf(wb[q], v.y, acc);
      }
      outn[obase + k * NBIN] = acc;
    }
  }
}

extern "C" void kernel_launch(void* const* d_in, const int* in_sizes, int n_in,
                              void* d_out, int out_size, void* d_ws, size_t ws_size,
                              hipStream_t stream) {
  const float* feat = (const float*)d_in[0];
  const float* rois = (const float*)d_in[1];
  float* out = (float*)d_out;
  int N = in_sizes[1] / 5;  // rois is (N,5)
  roialign_kernel<<<dim3(N), dim3(256), 0, stream>>>(feat, rois, out);
}

// Round 3
// 266.587 us; speedup vs baseline: 2.5287x; 1.2903x over previous
//
#include <hip/hip_runtime.h>

#define PH_ 7
#define PW_ 7
#define C_ 256
#define H_ 200
#define W_ 272
#define HW_ (H_*W_)
#define CT 8                  // channels per LDS tile
#define NT (C_/CT)            // 32 tiles
#define NBIN (PH_*PW_)        // 49
#define NCOMP (CT*NBIN)       // 392 compute items per tile
#define RMAX 32               // max region rows (roi<=32px + bilinear, proven bound)
#define RSTRIDE 36            // region row stride in floats (<=36 cols, 16B-aligned)
#define TILE_F (CT*RMAX*RSTRIDE)   // 9216 floats = 36.9 KB

__global__ __launch_bounds__(512, 8)
void roialign_kernel(const float* __restrict__ feat,
                     const float* __restrict__ rois,
                     float* __restrict__ out) {
  // yp[2*ph+iy] = {int y0, hy*vy, ly*vy, int y1i}
  // xp[2*pw+ix] = {int c,  wl(=hx*vx/4 @c), wr(=lx*vx/4 @c+1), 0}
  __shared__ float4 yp[PH_*2];
  __shared__ float4 xp[PW_*2];
  __shared__ int prm[5];   // base, ymin, xs4, rh, ng4
  __shared__ __align__(16) float tile[TILE_F];

  const int n = blockIdx.x;
  const int tid = threadIdx.x;
  const float* roi = rois + (size_t)n * 5;

  if (tid < 28) {
    float x1 = roi[1] * 0.0625f, y1 = roi[2] * 0.0625f;
    float x2 = roi[3] * 0.0625f, y2 = roi[4] * 0.0625f;
    float roi_w = fmaxf(x2 - x1, 1.0f);
    float roi_h = fmaxf(y2 - y1, 1.0f);
    float bin_w = roi_w * (1.0f / 7.0f);
    float bin_h = roi_h * (1.0f / 7.0f);
    if (tid == 0) prm[0] = (int)roi[0] * (C_ * HW_);
    if (tid < 14) {
      int ph = tid >> 1, iy = tid & 1;
      float y = y1 + (float)ph * bin_h + ((float)iy + 0.5f) * bin_h * 0.5f;
      float v = (y >= -1.0f && y <= (float)H_) ? 1.0f : 0.0f;
      float yc = fminf(fmaxf(y, 0.0f), (float)(H_ - 1));
      int y0 = (int)floorf(yc);
      if (y0 > H_ - 1) y0 = H_ - 1;
      int y1i = min(y0 + 1, H_ - 1);
      float ly = yc - (float)y0;
      float hy = 1.0f - ly;
      yp[tid] = make_float4(__int_as_float(y0), hy * v, ly * v,
                            __int_as_float(y1i));
    } else {
      int t = tid - 14;
      int pw = t >> 1, ix = t & 1;
      float x = x1 + (float)pw * bin_w + ((float)ix + 0.5f) * bin_w * 0.5f;
      float v = (x >= -1.0f && x <= (float)W_) ? 0.25f : 0.0f;
      float xc = fminf(fmaxf(x, 0.0f), (float)(W_ - 1));
      int x0 = (int)floorf(xc);
      float lx = xc - (float)x0;
      float hx = 1.0f - lx;
      int c; float wl, wr;
      if (x0 >= W_ - 1) { c = W_ - 2; wl = 0.0f; wr = hx * v; }
      else              { c = x0;     wl = hx * v; wr = lx * v; }
      xp[t] = make_float4(__int_as_float(c), wl, wr, 0.0f);
    }
  }
  __syncthreads();

  if (tid == 0) {
    int ymin = H_, ymax = 0, cmin = W_, cmax = 0;
#pragma unroll
    for (int i = 0; i < 14; ++i) {
      int y0 = __float_as_int(yp[i].x), y1i = __float_as_int(yp[i].w);
      ymin = min(ymin, y0); ymax = max(ymax, y1i);
      int c = __float_as_int(xp[i].x);
      cmin = min(cmin, c); cmax = max(cmax, c);
    }
    int xs4 = cmin & ~3;
    prm[1] = ymin;
    prm[2] = xs4;
    prm[3] = ymax - ymin + 1;              // rh <= 32
    prm[4] = (cmax + 1 - xs4 + 4) >> 2;    // ng4 <= 9
  }
  __syncthreads();

  const int base = prm[0];
  const int ymin = prm[1];
  const int xs4  = prm[2];
  const int rh   = prm[3];
  const int ng4  = prm[4];
  const int rg   = rh * ng4;        // float4s per channel
  const int nf4  = CT * rg;         // float4s per tile

  // per-thread fixed compute descriptor (same (c,bin) every tile)
  const bool active = tid < NCOMP;
  int o[8]; float wa[8], wb[8];
  int outoff = 0;
  if (active) {
    int c = tid / NBIN;             // const-divisor
    int bin = tid - c * NBIN;
    int ph = bin / PW_;
    int pw = bin - ph * PW_;
    float4 ya = yp[ph * 2 + 0], yb = yp[ph * 2 + 1];
    float4 xa = xp[pw * 2 + 0], xb = xp[pw * 2 + 1];
    int r00 = (__float_as_int(ya.x) - ymin) * RSTRIDE;
    int r01 = (__float_as_int(ya.w) - ymin) * RSTRIDE;
    int r10 = (__float_as_int(yb.x) - ymin) * RSTRIDE;
    int r11 = (__float_as_int(yb.w) - ymin) * RSTRIDE;
    int c0 = __float_as_int(xa.x) - xs4;
    int c1 = __float_as_int(xb.x) - xs4;
    int lb = c * (RMAX * RSTRIDE);
    o[0] = lb + r00 + c0; wa[0] = ya.y * xa.y; wb[0] = ya.y * xa.z;
    o[1] = lb + r01 + c0; wa[1] = ya.z * xa.y; wb[1] = ya.z * xa.z;
    o[2] = lb + r00 + c1; wa[2] = ya.y * xb.y; wb[2] = ya.y * xb.z;
    o[3] = lb + r01 + c1; wa[3] = ya.z * xb.y; wb[3] = ya.z * xb.z;
    o[4] = lb + r10 + c0; wa[4] = yb.y * xa.y; wb[4] = yb.y * xa.z;
    o[5] = lb + r11 + c0; wa[5] = yb.z * xa.y; wb[5] = yb.z * xa.z;
    o[6] = lb + r10 + c1; wa[6] = yb.y * xb.y; wb[6] = yb.y * xb.z;
    o[7] = lb + r11 + c1; wa[7] = yb.z * xb.y; wb[7] = yb.z * xb.z;
    outoff = c * NBIN + bin;
  }

  float* outn = out + (size_t)n * (C_ * NBIN);

  for (int ct = 0; ct < NT; ++ct) {
    // ---- stage CT channels' bbox into LDS (coalesced float4) ----
    for (int idx = tid; idx < nf4; idx += 512) {
      int c = idx / rg;
      int rem = idx - c * rg;
      int row = rem / ng4;
      int g = rem - row * ng4;
      const float* gp = feat + (size_t)base + (size_t)(ct * CT + c) * HW_ +
                        (size_t)(ymin + row) * W_ + (xs4 + 4 * g);
      float4 v = *(const float4*)gp;
      *(float4*)&tile[c * (RMAX * RSTRIDE) + row * RSTRIDE + 4 * g] = v;
    }
    __syncthreads();

    // ---- compute 8 channels x 49 bins from LDS ----
    if (active) {
      float acc = 0.0f;
#pragma unroll
      for (int q = 0; q < 8; ++q) {
        acc = fmaf(wa[q], tile[o[q]], acc);
        acc = fmaf(wb[q], tile[o[q] + 1], acc);
      }
      outn[ct * NCOMP + outoff] = acc;
    }
    __syncthreads();
  }
}

extern "C" void kernel_launch(void* const* d_in, const int* in_sizes, int n_in,
                              void* d_out, int out_size, void* d_ws, size_t ws_size,
                              hipStream_t stream) {
  const float* feat = (const float*)d_in[0];
  const float* rois = (const float*)d_in[1];
  float* out = (float*)d_out;
  int N = in_sizes[1] / 5;  // rois is (N,5)
  roialign_kernel<<<dim3(N), dim3(512), 0, stream>>>(feat, rois, out);
}